// Round 4
// baseline (337.664 us; speedup 1.0000x reference)
//
#include <hip/hip_runtime.h>

typedef float f2 __attribute__((ext_vector_type(2)));

#define PAD 5
#define WSZ 11

// Precomputed normalized 11-tap Gaussian (sigma=1.5) — matches fp32 ref far
// within the 1.4e-2 threshold. Hard-coded to keep weights out of VGPRs.
__device__ __forceinline__ float gw(int k) {
    const float G[WSZ] = {
        0.0010283782f, 0.0075987580f, 0.0360007600f, 0.1093607000f,
        0.2130055600f, 0.2660117400f,
        0.2130055600f, 0.1093607000f, 0.0360007600f, 0.0075987580f, 0.0010283782f };
    return G[k];
}

// Per-wave SSIM strip: 64-col x RT-row strip of the F-pooled (512/F)^2 image,
// computed DIRECTLY from the raw 512x512 planar inputs (pooling is linear and
// block-aligned, so scale-k input = exact FxF box average — no pyramid pass,
// no intermediate buffers, no inter-dispatch dependency).
//   F==1: depth-2 global prefetch into register slots P0/P1 (slot = it&1,
//         static after unroll-by-12) — the proven 131us hot path, unchanged.
//   F>=2: pooled row computed at consume time (4/16/64 f2-loads per pixel).
//         These waves stall on vmcnt per iteration, but they are shadow work
//         under scale-0's 74-iteration waves and their reads are L2/L3-hot.
// Horizontal 11-tap via a 74-wide private LDS row (same-wave DS ordering;
// wavefront fences pin the compiler, emit no waitcnt). Vertical 11-tap via a
// 12-deep register ring (static indices). Returns wave-reduced SSIM sum
// (valid on lane 0).
template<int RT, int F>
__device__ __forceinline__ float ssim_strip(
    const float* __restrict__ img1, const float* __restrict__ img2,
    int bx, int sy, int z, f2* st, int lane)
{
    constexpr int Wp = 512 / F, Hp = 512 / F;   // pooled dims
    const int ox = bx * 64;
    const int r0 = sy * RT;
    const size_t base = (size_t)z * 262144;     // raw plane
    constexpr int NIT = RT + 10;
    const float C1 = 1e-4f, C2 = 9e-4f;

    // Per-lane column geometry (iteration-invariant, pooled coords).
    const int c0 = ox - PAD + lane;
    const bool m0 = (c0 >= 0) & (c0 < Wp);
    const int c0c = min(max(c0, 0), Wp - 1);
    const int c1 = ox + 59 + lane;              // halo cols, lanes 0..9
    const bool m1 = (lane < 10) & (c1 < Wp);
    const int c1c = min(c1, Wp - 1);

    f2 P0a = {0.f, 0.f}, P0b = {0.f, 0.f};
    f2 P1a = {0.f, 0.f}, P1b = {0.f, 0.f};

    auto issue = [&](int y, f2& A, f2& B) {     // F==1 only
        int yc = min(max(y, 0), Hp - 1);        // clamp; mask at consume
        const size_t roff = base + (size_t)yc * 512;  // wave-uniform -> SALU
        A = (f2){ img1[roff + c0c], img2[roff + c0c] };
        if (lane < 10) B = (f2){ img1[roff + c1c], img2[roff + c1c] };
    };

    // FxF box average at pooled (yc, cc) from the raw image. unroll_count(2)
    // for F==8 keeps <=16 loads in flight (VGPR containment: this branch must
    // not balloon the kernel's register max — the (256,6) spill lesson).
    auto pooled = [&](int yc, int cc) -> f2 {
        const float* b1 = img1 + base + (size_t)(yc * F) * 512 + cc * F;
        const float* b2 = img2 + base + (size_t)(yc * F) * 512 + cc * F;
        float sx = 0.f, sy2 = 0.f;
        if constexpr (F == 8) {
#pragma clang loop unroll_count(2)
            for (int rr = 0; rr < F; ++rr) {
#pragma unroll
                for (int k = 0; k < F / 2; ++k) {
                    f2 a = *(const f2*)(b1 + rr * 512 + 2 * k);
                    f2 b = *(const f2*)(b2 + rr * 512 + 2 * k);
                    sx += a.x + a.y; sy2 += b.x + b.y;
                }
            }
        } else {
#pragma unroll
            for (int rr = 0; rr < F; ++rr) {
#pragma unroll
                for (int k = 0; k < (F > 1 ? F / 2 : 1); ++k) {
                    f2 a = *(const f2*)(b1 + rr * 512 + 2 * k);
                    f2 b = *(const f2*)(b2 + rr * 512 + 2 * k);
                    sx += a.x + a.y; sy2 += b.x + b.y;
                }
            }
        }
        return (f2){ sx * (1.f / (F * F)), sy2 * (1.f / (F * F)) };
    };

    if constexpr (F == 1) {
        issue(r0 - PAD + 0, P0a, P0b);
        issue(r0 - PAD + 1, P1a, P1b);
    }

    f2 rmu[12], rsq[12];
    float rxx[12];
    float local = 0.f;
    const f2 zero = {0.f, 0.f};

#pragma clang loop unroll(disable)
    for (int b0 = 0; b0 < NIT; b0 += 12) {
#pragma unroll
        for (int j = 0; j < 12; ++j) {
            const int it = b0 + j;
            if (it < NIT) {
                const int y = r0 - PAD + it;
                const bool yok = (y >= 0) & (y < Hp);  // wave-uniform

                f2 wa, wb;
                if constexpr (F == 1) {
                    f2& ca = (j & 1) ? P1a : P0a;      // static slot select
                    f2& cb = (j & 1) ? P1b : P0b;
                    wa = (yok & m0) ? ca : zero;       // vmcnt wait lands here
                    wb = (yok & m1) ? cb : zero;
                    issue(y + 2, ca, cb);              // refill: depth-2 prefetch
                } else {
                    const int yc = min(max(y, 0), Hp - 1);
                    f2 pa = pooled(yc, c0c);
                    wa = (yok & m0) ? pa : zero;
                    wb = zero;
                    if (lane < 10) {
                        f2 pb = pooled(yc, c1c);
                        wb = (yok & m1) ? pb : zero;
                    }
                }

                __builtin_amdgcn_fence(__ATOMIC_ACQ_REL, "wavefront");
                __builtin_amdgcn_wave_barrier();
                st[lane] = wa;
                if (lane < 10) st[64 + lane] = wb;
                __builtin_amdgcn_fence(__ATOMIC_ACQ_REL, "wavefront");
                __builtin_amdgcn_wave_barrier();

                // Horizontal 11-tap (same-wave DS ordering guarantees RAW).
                f2 hmu = zero, hsq = zero;
                float hxx = 0.f;
#pragma unroll
                for (int k = 0; k < WSZ; ++k) {
                    f2 p = st[lane + k];
                    hmu += p * gw(k);
                    hsq += (p * p) * gw(k);
                    hxx += (p.x * p.y) * gw(k);
                }
                rmu[it % 12] = hmu;                    // it%12 == j: static
                rsq[it % 12] = hsq;
                rxx[it % 12] = hxx;

                // Vertical 11-tap + SSIM.
                if (it >= 10) {
                    f2 vmu = zero, vsq = zero;
                    float vxx = 0.f;
#pragma unroll
                    for (int k = 0; k < WSZ; ++k) {
                        const int s = (j + 2 + k) % 12;  // static after unroll
                        vmu += rmu[s] * gw(k);
                        vsq += rsq[s] * gw(k);
                        vxx += rxx[s] * gw(k);
                    }
                    const float mu1 = vmu.x, mu2 = vmu.y;
                    const float mu11 = mu1 * mu1, mu22 = mu2 * mu2, mu12 = mu1 * mu2;
                    const float sig1 = vsq.x - mu11;
                    const float sig2 = vsq.y - mu22;
                    const float sig12 = vxx - mu12;
                    const float num = (2.f * mu12 + C1) * (2.f * sig12 + C2);
                    const float den = (mu11 + mu22 + C1) * (sig1 + sig2 + C2);
                    local += num * __builtin_amdgcn_rcpf(den);
                }
            }
        }
    }

#pragma unroll
    for (int off = 32; off > 0; off >>= 1) local += __shfl_down(local, off);
    return local;
}

// All 4 scales in ONE dispatch (the only heavy kernel). 128-thread blocks =
// 2 independent waves on adjacent row strips. Scales interleaved through the
// block-index space in groups of 29 (16:8:4:1 matches per-channel block
// counts 32:16:8:2) so every scale is co-resident from t=0.
// Each wave plain-stores its partial to its own slot -> no init kernel, no
// atomics; every slot is written every run (graph-replay safe).
// __launch_bounds__(128,4): 128-VGPR cap — far above the ~60 used by the hot
// F=1 path (the 85-VGPR cap variant spilled the vertical ring: 2.2x slower).
__global__ __launch_bounds__(128, 4) void ssim_fused_kernel(
    const float* __restrict__ img1, const float* __restrict__ img2,
    double* __restrict__ partials)
{
    __shared__ f2 st_all[2][80];
    const int lane = threadIdx.x & 63;
    const int wv   = threadIdx.x >> 6;
    f2* st = st_all[wv];

    const int i = blockIdx.x;
    const int g = i / 29;                  // magic-mul div
    const int r = i - g * 29;

    float local;
    if (r < 16) {                          // scale 0: RT=64, 512x512
        const int l = g * 16 + r;
        local = ssim_strip<64, 1>(img1, img2, l & 7, ((l >> 3) & 3) * 2 + wv,
                                  l >> 5, st, lane);
    } else if (r < 24) {                   // scale 1: RT=32, 256x256 (F=2)
        const int l = g * 8 + (r - 16);
        local = ssim_strip<32, 2>(img1, img2, l & 3, ((l >> 2) & 3) * 2 + wv,
                                  l >> 4, st, lane);
    } else if (r < 28) {                   // scale 2: RT=16, 128x128 (F=4)
        const int l = g * 4 + (r - 24);
        local = ssim_strip<16, 4>(img1, img2, l & 1, ((l >> 1) & 3) * 2 + wv,
                                  l >> 3, st, lane);
    } else {                               // scale 3: RT=16, 64x64 (F=8)
        const int l = g;
        local = ssim_strip<16, 8>(img1, img2, 0, (l & 1) * 2 + wv,
                                  l >> 1, st, lane);
    }
    if (lane == 0) partials[(size_t)i * 2 + wv] = (double)local;
}

// Single-block reduce of all per-wave partials; decodes wave->scale from the
// same group-of-29 mapping. ~45 KB of L2-hot doubles, few us.
__global__ __launch_bounds__(256) void finalize_kernel(
    const double* __restrict__ partials, float* __restrict__ out, int nw,
    double c0, double c1, double c2, double c3)
{
    double s[4] = {0.0, 0.0, 0.0, 0.0};
    for (int idx = threadIdx.x; idx < nw; idx += 256) {
        const int b = idx >> 1;
        const int g = b / 29;
        const int r = b - g * 29;
        const int sc = (r < 16) ? 0 : (r < 24) ? 1 : (r < 28) ? 2 : 3;
        s[sc] += partials[idx];
    }
    __shared__ double sm[4][256];
    sm[0][threadIdx.x] = s[0]; sm[1][threadIdx.x] = s[1];
    sm[2][threadIdx.x] = s[2]; sm[3][threadIdx.x] = s[3];
    __syncthreads();
    if (threadIdx.x == 0) {
        const double w[4] = {0.0448, 0.2856, 0.3001, 0.2363};
        const double cnt[4] = {c0, c1, c2, c3};
        double loss = 0.0;
#pragma unroll
        for (int sc = 0; sc < 4; ++sc) {
            double t = 0.0;
            for (int k = 0; k < 256; ++k) t += sm[sc][k];
            loss += w[sc] * (1.0 - t / cnt[sc]);
        }
        out[0] = (float)loss;
    }
}

extern "C" void kernel_launch(void* const* d_in, const int* in_sizes, int n_in,
                              void* d_out, int out_size, void* d_ws, size_t ws_size,
                              hipStream_t stream) {
    const float* img1 = (const float*)d_in[0];
    const float* img2 = (const float*)d_in[1];
    float* out = (float*)d_out;

    const int H0 = 512, W0 = 512;
    const int NC = in_sizes[0] / (H0 * W0);  // 48

    double* partials = (double*)d_ws;        // NC*58 blocks * 2 waves doubles

    // Per channel 32+16+8+2 = 58 blocks = 2 groups of 29.
    const int NBLK = NC * 58;
    ssim_fused_kernel<<<dim3(NBLK), 128, 0, stream>>>(img1, img2, partials);

    const double c0 = (double)NC * 512.0 * 512.0;
    const double c1 = (double)NC * 256.0 * 256.0;
    const double c2 = (double)NC * 128.0 * 128.0;
    const double c3 = (double)NC * 64.0 * 64.0;
    finalize_kernel<<<1, 256, 0, stream>>>(partials, out, NBLK * 2, c0, c1, c2, c3);
}

// Round 5
// 240.897 us; speedup vs baseline: 1.4017x; 1.4017x over previous
//
#include <hip/hip_runtime.h>

typedef float f2 __attribute__((ext_vector_type(2)));
typedef float f4 __attribute__((ext_vector_type(4)));

#define PAD 5
#define WSZ 11

// Precomputed normalized 11-tap Gaussian (sigma=1.5) — matches fp32 ref far
// within the 1.4e-2 threshold. Hard-coded to keep weights out of VGPRs.
__device__ __forceinline__ float gw(int k) {
    const float G[WSZ] = {
        0.0010283782f, 0.0075987580f, 0.0360007600f, 0.1093607000f,
        0.2130055600f, 0.2660117400f,
        0.2130055600f, 0.1093607000f, 0.0360007600f, 0.0075987580f, 0.0010283782f };
    return G[k];
}

// Pyramid pre-pass v2: one wave per (col-half, 8-row group, channel) =
// 6144 waves (24/CU, 2x round-3's 12). Lane owns 4 CONTIGUOUS cols ->
// every global load is a fully-coalesced wave-wide f4 (1 KB/instr; v1's
// 8-col-per-lane layout had stride-32B half-density loads). All 16 loads
// issued up-front (full MLP). Produces p1 (2x2), p2 (4x4) and p3 (8x8 via
// one __shfl_xor pair-reduce) so the SSIM kernel is untouched.
// Round-3's v1 ran at ~1.3 TB/s (latency-bound, ~100us); this should be ~4x.
__global__ __launch_bounds__(64) void pyramid_kernel(
    const float* __restrict__ img1, const float* __restrict__ img2,
    f2* __restrict__ p1, f2* __restrict__ p2, f2* __restrict__ p3)
{
    const int lane = threadIdx.x;        // owns raw cols cb*256 + lane*4 ..+3
    const int cb = blockIdx.x;           // column half (0/1)
    const int rb = blockIdx.y;           // 8-row group (0..63)
    const int z  = blockIdx.z;

    const size_t ibase = (size_t)z * 262144 + (size_t)(rb * 8) * 512 + cb * 256 + lane * 4;
    const float* b1 = img1 + ibase;
    const float* b2 = img2 + ibase;

    f4 A[8], B[8];
#pragma unroll
    for (int r = 0; r < 8; ++r) {        // 16 independent loads in flight
        A[r] = *(const f4*)(b1 + r * 512);
        B[r] = *(const f4*)(b2 + r * 512);
    }

    f2 u0, u1;
#pragma unroll
    for (int q = 0; q < 2; ++q) {        // q = p2 row within group
        f2 acc = {0.f, 0.f};
#pragma unroll
        for (int h = 0; h < 2; ++h) {    // p1 row within p2 row
            const int rp = q * 2 + h;
            f4 a0 = A[2 * rp], a1 = A[2 * rp + 1];
            f4 c0 = B[2 * rp], c1 = B[2 * rp + 1];
            f2 v0 = { (a0.x + a0.y + a1.x + a1.y) * 0.25f,
                      (c0.x + c0.y + c1.x + c1.y) * 0.25f };
            f2 v1 = { (a0.z + a0.w + a1.z + a1.w) * 0.25f,
                      (c0.z + c0.w + c1.z + c1.w) * 0.25f };
            *(f4*)(p1 + (size_t)z * 65536 + (size_t)(rb * 4 + rp) * 256
                       + cb * 128 + lane * 2) = (f4){ v0.x, v0.y, v1.x, v1.y };
            acc += v0 + v1;
        }
        f2 u = acc * 0.25f;              // p2 pixel (4x4 avg)
        p2[(size_t)z * 16384 + (size_t)(rb * 2 + q) * 128 + cb * 64 + lane] = u;
        if (q == 0) u0 = u; else u1 = u;
    }
    f2 t = u0 + u1;                       // lane's 2 p2 pixels
    t.x += __shfl_xor(t.x, 1);            // + neighbor lane's column
    t.y += __shfl_xor(t.y, 1);
    if ((lane & 1) == 0)
        p3[(size_t)z * 4096 + (size_t)rb * 64 + cb * 32 + (lane >> 1)] = t * 0.25f;
}

// Per-wave SSIM strip body: 64-col x RT-row strip. Depth-2 global prefetch
// into register slots P0/P1 (slot = it&1, static after unroll-by-12).
// Horizontal 11-tap via a 74-wide private LDS row (same-wave DS ordering;
// wavefront fences pin the compiler, emit no waitcnt -> prefetch loads stay
// in flight). Vertical 11-tap via a 12-deep register ring (static indices).
// [Round-4 lesson: pooling-at-consume here destroys the prefetch structure
//  and triples HBM fetch — s1-3 MUST read precomputed pyramid buffers.]
template<int RT, bool PLANAR>
__device__ __forceinline__ float ssim_body(
    const float* __restrict__ img1, const float* __restrict__ img2,
    const f2* __restrict__ pair,
    int H, int W, int bx, int sy, int z, f2* st, int lane)
{
    const int ox = bx * 64;
    const int r0 = sy * RT;
    const size_t base = (size_t)z * H * W;

    constexpr int NIT = RT + 10;
    const float C1 = 1e-4f, C2 = 9e-4f;

    // Per-lane column geometry (iteration-invariant).
    const int c0 = ox - PAD + lane;
    const bool m0 = (c0 >= 0) & (c0 < W);
    const int c0c = min(max(c0, 0), W - 1);
    const int c1 = ox + 59 + lane;                 // halo cols, lanes 0..9
    const bool m1 = (lane < 10) & (c1 < W);
    const int c1c = min(c1, W - 1);

    f2 P0a = {0.f, 0.f}, P0b = {0.f, 0.f};
    f2 P1a = {0.f, 0.f}, P1b = {0.f, 0.f};

    auto issue = [&](int y, f2& A, f2& B) {
        int yc = min(max(y, 0), H - 1);            // clamp; mask at consume
        const size_t roff = base + (size_t)yc * W; // wave-uniform -> SALU
        if (PLANAR) {
            A = (f2){ img1[roff + c0c], img2[roff + c0c] };
            if (lane < 10) B = (f2){ img1[roff + c1c], img2[roff + c1c] };
        } else {
            A = pair[roff + c0c];
            if (lane < 10) B = pair[roff + c1c];
        }
    };

    issue(r0 - PAD + 0, P0a, P0b);
    issue(r0 - PAD + 1, P1a, P1b);

    f2 rmu[12], rsq[12];
    float rxx[12];
    float local = 0.f;
    const f2 zero = {0.f, 0.f};

#pragma clang loop unroll(disable)
    for (int b0 = 0; b0 < NIT; b0 += 12) {
#pragma unroll
        for (int j = 0; j < 12; ++j) {
            const int it = b0 + j;
            if (it < NIT) {
                const int y = r0 - PAD + it;
                const bool yok = (y >= 0) & (y < H);   // wave-uniform

                f2& ca = (j & 1) ? P1a : P0a;          // static slot select
                f2& cb = (j & 1) ? P1b : P0b;
                f2 wa = (yok & m0) ? ca : zero;        // vmcnt wait lands here
                f2 wb = (yok & m1) ? cb : zero;
                issue(y + 2, ca, cb);                  // refill slot: depth-2 prefetch

                __builtin_amdgcn_fence(__ATOMIC_ACQ_REL, "wavefront");
                __builtin_amdgcn_wave_barrier();
                st[lane] = wa;
                if (lane < 10) st[64 + lane] = wb;
                __builtin_amdgcn_fence(__ATOMIC_ACQ_REL, "wavefront");
                __builtin_amdgcn_wave_barrier();

                // Horizontal 11-tap (same-wave DS ordering guarantees RAW).
                f2 hmu = zero, hsq = zero;
                float hxx = 0.f;
#pragma unroll
                for (int k = 0; k < WSZ; ++k) {
                    f2 p = st[lane + k];
                    hmu += p * gw(k);
                    hsq += (p * p) * gw(k);
                    hxx += (p.x * p.y) * gw(k);
                }
                rmu[it % 12] = hmu;                    // it%12 == j: static
                rsq[it % 12] = hsq;
                rxx[it % 12] = hxx;

                // Vertical 11-tap + SSIM.
                if (it >= 10) {
                    f2 vmu = zero, vsq = zero;
                    float vxx = 0.f;
#pragma unroll
                    for (int k = 0; k < WSZ; ++k) {
                        const int s = (j + 2 + k) % 12;  // static after unroll
                        vmu += rmu[s] * gw(k);
                        vsq += rsq[s] * gw(k);
                        vxx += rxx[s] * gw(k);
                    }
                    const float mu1 = vmu.x, mu2 = vmu.y;
                    const float mu11 = mu1 * mu1, mu22 = mu2 * mu2, mu12 = mu1 * mu2;
                    const float sig1 = vsq.x - mu11;
                    const float sig2 = vsq.y - mu22;
                    const float sig12 = vxx - mu12;
                    const float num = (2.f * mu12 + C1) * (2.f * sig12 + C2);
                    const float den = (mu11 + mu22 + C1) * (sig1 + sig2 + C2);
                    local += num * __builtin_amdgcn_rcpf(den);
                }
            }
        }
    }

#pragma unroll
    for (int off = 32; off > 0; off >>= 1) local += __shfl_down(local, off);
    return local;
}

// All 4 scales in ONE dispatch. 128-thread blocks = 2 independent waves on
// adjacent row strips. Scales interleaved through the block-index space in
// groups of 29 (16:8:4:1 matches per-channel block counts 32:16:8:2) so every
// scale is co-resident from t=0; small scales run inside scale-0's shadow.
// Each wave plain-stores its partial to its own slot -> no init kernel, no
// atomics; every slot is written every run (graph-replay safe).
// __launch_bounds__(128,4): 128-VGPR cap — far above the ~60 used (the
// 85-VGPR cap variant spilled the vertical ring to scratch: 2.2x slower).
__global__ __launch_bounds__(128, 4) void ssim_fused_kernel(
    const float* __restrict__ img1, const float* __restrict__ img2,
    const f2* __restrict__ p1, const f2* __restrict__ p2, const f2* __restrict__ p3,
    double* __restrict__ partials)
{
    __shared__ f2 st_all[2][80];
    const int lane = threadIdx.x & 63;
    const int wv   = threadIdx.x >> 6;
    f2* st = st_all[wv];

    const int i = blockIdx.x;
    const int g = i / 29;                  // magic-mul div
    const int r = i - g * 29;

    float local;
    if (r < 16) {                          // scale 0: RT=64, 512x512, planar
        const int l = g * 16 + r;
        local = ssim_body<64, true>(img1, img2, nullptr, 512, 512,
                                    l & 7, ((l >> 3) & 3) * 2 + wv, l >> 5, st, lane);
    } else if (r < 24) {                   // scale 1: RT=32, 256x256
        const int l = g * 8 + (r - 16);
        local = ssim_body<32, false>(nullptr, nullptr, p1, 256, 256,
                                     l & 3, ((l >> 2) & 3) * 2 + wv, l >> 4, st, lane);
    } else if (r < 28) {                   // scale 2: RT=16, 128x128
        const int l = g * 4 + (r - 24);
        local = ssim_body<16, false>(nullptr, nullptr, p2, 128, 128,
                                     l & 1, ((l >> 1) & 3) * 2 + wv, l >> 3, st, lane);
    } else {                               // scale 3: RT=16, 64x64
        const int l = g;
        local = ssim_body<16, false>(nullptr, nullptr, p3, 64, 64,
                                     0, (l & 1) * 2 + wv, l >> 1, st, lane);
    }
    if (lane == 0) partials[(size_t)i * 2 + wv] = (double)local;
}

// Single-block reduce of all per-wave partials; decodes wave->scale from the
// same group-of-29 mapping. ~45 KB of L2-hot doubles, few us.
__global__ __launch_bounds__(256) void finalize_kernel(
    const double* __restrict__ partials, float* __restrict__ out, int nw,
    double c0, double c1, double c2, double c3)
{
    double s[4] = {0.0, 0.0, 0.0, 0.0};
    for (int idx = threadIdx.x; idx < nw; idx += 256) {
        const int b = idx >> 1;
        const int g = b / 29;
        const int r = b - g * 29;
        const int sc = (r < 16) ? 0 : (r < 24) ? 1 : (r < 28) ? 2 : 3;
        s[sc] += partials[idx];
    }
    __shared__ double sm[4][256];
    sm[0][threadIdx.x] = s[0]; sm[1][threadIdx.x] = s[1];
    sm[2][threadIdx.x] = s[2]; sm[3][threadIdx.x] = s[3];
    __syncthreads();
    if (threadIdx.x == 0) {
        const double w[4] = {0.0448, 0.2856, 0.3001, 0.2363};
        const double cnt[4] = {c0, c1, c2, c3};
        double loss = 0.0;
#pragma unroll
        for (int sc = 0; sc < 4; ++sc) {
            double t = 0.0;
            for (int k = 0; k < 256; ++k) t += sm[sc][k];
            loss += w[sc] * (1.0 - t / cnt[sc]);
        }
        out[0] = (float)loss;
    }
}

extern "C" void kernel_launch(void* const* d_in, const int* in_sizes, int n_in,
                              void* d_out, int out_size, void* d_ws, size_t ws_size,
                              hipStream_t stream) {
    const float* img1 = (const float*)d_in[0];
    const float* img2 = (const float*)d_in[1];
    float* out = (float*)d_out;

    const int H0 = 512, W0 = 512;
    const int NC = in_sizes[0] / (H0 * W0);  // 48

    double* partials = (double*)d_ws;                 // NC*58*2 doubles (<64KB)
    f2* p1 = (f2*)((char*)d_ws + 65536);              // NC*256*256
    f2* p2 = p1 + (size_t)NC * 256 * 256;             // NC*128*128
    f2* p3 = p2 + (size_t)NC * 128 * 128;             // NC*64*64

    // Pyramid: 2 col-halves x 64 row-groups x NC channels, 1 wave each.
    pyramid_kernel<<<dim3(2, 64, NC), 64, 0, stream>>>(img1, img2, p1, p2, p3);

    // Fused SSIM: per channel 32+16+8+2 = 58 blocks = 2 groups of 29.
    const int NBLK = NC * 58;
    ssim_fused_kernel<<<dim3(NBLK), 128, 0, stream>>>(img1, img2, p1, p2, p3, partials);

    const double c0 = (double)NC * 512.0 * 512.0;
    const double c1 = (double)NC * 256.0 * 256.0;
    const double c2 = (double)NC * 128.0 * 128.0;
    const double c3 = (double)NC * 64.0 * 64.0;
    finalize_kernel<<<1, 256, 0, stream>>>(partials, out, NBLK * 2, c0, c1, c2, c3);
}